// Round 1
// baseline (2376.764 us; speedup 1.0000x reference)
//
#include <hip/hip_runtime.h>
#include <cstddef>

#define NP 100000
#define NC 20000
#define NE 2000000
#define DIM 128
#define HID 128
#define OUT 64

// ---------------- zero workspace ----------------
__global__ void zero4_kernel(float4* p, size_t n4) {
    size_t i = blockIdx.x * (size_t)blockDim.x + threadIdx.x;
    size_t stride = (size_t)gridDim.x * blockDim.x;
    float4 z = make_float4(0.f, 0.f, 0.f, 0.f);
    for (; i < n4; i += stride) p[i] = z;
}

// ---------------- edge scatter (atomics) ----------------
// one wave (64 lanes) per edge; lane d handles dims d and d+64
__global__ __launch_bounds__(256) void scatter_kernel(
    const int* __restrict__ ep, const int* __restrict__ ec,
    const float* __restrict__ ew,
    const float* __restrict__ pemb, const float* __restrict__ cemb,
    float* __restrict__ pdeg, float* __restrict__ cdeg,
    float* __restrict__ pmsg, float* __restrict__ cmsg)
{
    int tid = blockIdx.x * blockDim.x + threadIdx.x;
    int e = tid >> 6;
    int lane = tid & 63;
    if (e >= NE) return;
    int p = ep[e];
    int c = ec[e];
    float w = ew[e];
    if (lane == 0) {
        atomicAdd(&pdeg[p], w);
        atomicAdd(&cdeg[c], w);
    }
    const float* crow = cemb + (size_t)c * DIM;
    const float* prow = pemb + (size_t)p * DIM;
    float ce0 = crow[lane], ce1 = crow[lane + 64];
    float pe0 = prow[lane], pe1 = prow[lane + 64];
    atomicAdd(&pmsg[(size_t)p * DIM + lane],      w * ce0);
    atomicAdd(&pmsg[(size_t)p * DIM + lane + 64], w * ce1);
    atomicAdd(&cmsg[(size_t)c * DIM + lane],      w * pe0);
    atomicAdd(&cmsg[(size_t)c * DIM + lane + 64], w * pe1);
}

// ---------------- fused MLP (wave per row) ----------------
// x = [emb_row (128) | msg_row/deg (128)]  -> h = relu(LN(x@w1+b1)) -> out = LN(h@w2+b2)
__global__ __launch_bounds__(256) void mlp_kernel(
    const float* __restrict__ emb, const float* __restrict__ msg,
    const float* __restrict__ deg,
    const float* __restrict__ w1, const float* __restrict__ b1,
    const float* __restrict__ g1, const float* __restrict__ be1,
    const float* __restrict__ w2, const float* __restrict__ b2,
    const float* __restrict__ g2, const float* __restrict__ be2,
    float* __restrict__ out, int nrows)
{
    __shared__ float s_x[4][256];
    __shared__ float s_h[4][128];
    int wave = threadIdx.x >> 6;
    int lane = threadIdx.x & 63;
    int row = blockIdx.x * 4 + wave;   // grids sized exactly; nrows % 4 == 0

    const float* erow = emb + (size_t)row * DIM;
    const float* mrow = msg + (size_t)row * DIM;
    float inv = 1.0f / (deg[row] + 1e-8f);

    s_x[wave][lane]       = erow[lane];
    s_x[wave][lane + 64]  = erow[lane + 64];
    s_x[wave][lane + 128] = mrow[lane] * inv;
    s_x[wave][lane + 192] = mrow[lane + 64] * inv;
    __syncthreads();

    // layer 1: h[lane], h[lane+64]
    float h0 = b1[lane];
    float h1 = b1[lane + 64];
    #pragma unroll 4
    for (int k = 0; k < 256; k += 4) {
        float4 xk = *(const float4*)&s_x[wave][k];
        const float* wk = w1 + (size_t)k * HID;
        h0 += xk.x * wk[lane];            h1 += xk.x * wk[lane + 64];
        h0 += xk.y * wk[HID + lane];      h1 += xk.y * wk[HID + lane + 64];
        h0 += xk.z * wk[2*HID + lane];    h1 += xk.z * wk[2*HID + lane + 64];
        h0 += xk.w * wk[3*HID + lane];    h1 += xk.w * wk[3*HID + lane + 64];
    }

    // LN over 128 (across the wave: 2 values/lane)
    float s = h0 + h1;
    float ss = h0 * h0 + h1 * h1;
    #pragma unroll
    for (int off = 32; off; off >>= 1) {
        s  += __shfl_down(s, off);
        ss += __shfl_down(ss, off);
    }
    s  = __shfl(s, 0);
    ss = __shfl(ss, 0);
    float mu  = s * (1.0f / 128.0f);
    float var = ss * (1.0f / 128.0f) - mu * mu;
    float rstd = rsqrtf(var + 1e-5f);
    float n0 = (h0 - mu) * rstd * g1[lane]      + be1[lane];
    float n1 = (h1 - mu) * rstd * g1[lane + 64] + be1[lane + 64];
    n0 = fmaxf(n0, 0.0f);
    n1 = fmaxf(n1, 0.0f);
    s_h[wave][lane]      = n0;
    s_h[wave][lane + 64] = n1;
    __syncthreads();

    // layer 2: out[lane] (64 outputs)
    float acc = b2[lane];
    #pragma unroll 4
    for (int j = 0; j < 128; j += 4) {
        float4 hj = *(const float4*)&s_h[wave][j];
        const float* wj = w2 + (size_t)j * OUT;
        acc += hj.x * wj[lane];
        acc += hj.y * wj[OUT + lane];
        acc += hj.z * wj[2*OUT + lane];
        acc += hj.w * wj[3*OUT + lane];
    }

    // LN over 64 (one value/lane)
    float s2 = acc, ss2 = acc * acc;
    #pragma unroll
    for (int off = 32; off; off >>= 1) {
        s2  += __shfl_down(s2, off);
        ss2 += __shfl_down(ss2, off);
    }
    s2  = __shfl(s2, 0);
    ss2 = __shfl(ss2, 0);
    float mu2  = s2 * (1.0f / 64.0f);
    float var2 = ss2 * (1.0f / 64.0f) - mu2 * mu2;
    float rstd2 = rsqrtf(var2 + 1e-5f);
    float o = (acc - mu2) * rstd2 * g2[lane] + be2[lane];
    out[(size_t)row * OUT + lane] = o;
}

extern "C" void kernel_launch(void* const* d_in, const int* in_sizes, int n_in,
                              void* d_out, int out_size, void* d_ws, size_t ws_size,
                              hipStream_t stream) {
    const int*   ep   = (const int*)d_in[0];
    const int*   ec   = (const int*)d_in[1];
    const float* ew   = (const float*)d_in[2];
    const float* pemb = (const float*)d_in[3];
    const float* cemb = (const float*)d_in[4];
    const float* w1p  = (const float*)d_in[5];
    const float* b1p  = (const float*)d_in[6];
    const float* g1p  = (const float*)d_in[7];
    const float* be1p = (const float*)d_in[8];
    const float* w2p  = (const float*)d_in[9];
    const float* b2p  = (const float*)d_in[10];
    const float* g2p  = (const float*)d_in[11];
    const float* be2p = (const float*)d_in[12];
    const float* w1c  = (const float*)d_in[13];
    const float* b1c  = (const float*)d_in[14];
    const float* g1c  = (const float*)d_in[15];
    const float* be1c = (const float*)d_in[16];
    const float* w2c  = (const float*)d_in[17];
    const float* b2c  = (const float*)d_in[18];
    const float* g2c  = (const float*)d_in[19];
    const float* be2c = (const float*)d_in[20];

    float* ws   = (float*)d_ws;
    float* pdeg = ws;                       // NP
    float* cdeg = pdeg + NP;                // NC
    float* pmsg = cdeg + NC;                // NP*DIM
    float* cmsg = pmsg + (size_t)NP * DIM;  // NC*DIM
    size_t total_f = (size_t)NP + NC + (size_t)NP * DIM + (size_t)NC * DIM;

    // zero accumulators (must happen every call: atomics accumulate)
    zero4_kernel<<<2048, 256, 0, stream>>>((float4*)ws, total_f / 4);

    // scatter: one wave per edge
    {
        long long threads = (long long)NE * 64;
        int blocks = (int)((threads + 255) / 256);
        scatter_kernel<<<blocks, 256, 0, stream>>>(ep, ec, ew, pemb, cemb,
                                                   pdeg, cdeg, pmsg, cmsg);
    }

    float* out_p = (float*)d_out;            // [NP, 64]
    float* out_c = out_p + (size_t)NP * OUT; // [NC, 64]

    mlp_kernel<<<NP / 4, 256, 0, stream>>>(pemb, pmsg, pdeg,
                                           w1p, b1p, g1p, be1p,
                                           w2p, b2p, g2p, be2p,
                                           out_p, NP);
    mlp_kernel<<<NC / 4, 256, 0, stream>>>(cemb, cmsg, cdeg,
                                           w1c, b1c, g1c, be1c,
                                           w2c, b2c, g2c, be2c,
                                           out_c, NC);
}

// Round 2
// 1398.324 us; speedup vs baseline: 1.6997x; 1.6997x over previous
//
#include <hip/hip_runtime.h>
#include <cstddef>

#define NP 100000
#define NC 20000
#define NE 2000000
#define DIM 128
#define HID 128
#define OUT 64

// ---------------- zero workspace region ----------------
__global__ void zero4_kernel(float4* p, size_t n4) {
    size_t i = blockIdx.x * (size_t)blockDim.x + threadIdx.x;
    size_t stride = (size_t)gridDim.x * blockDim.x;
    float4 z = make_float4(0.f, 0.f, 0.f, 0.f);
    for (; i < n4; i += stride) p[i] = z;
}

// ---------------- histogram ----------------
__global__ __launch_bounds__(256) void hist_kernel(
    const int* __restrict__ ep, const int* __restrict__ ec,
    int* __restrict__ hist_p, int* __restrict__ hist_c)
{
    int e = blockIdx.x * 256 + threadIdx.x;
    if (e >= NE) return;
    atomicAdd(&hist_p[ep[e]], 1);
    atomicAdd(&hist_c[ec[e]], 1);
}

// ---------------- scan phase 1: per-block (1024 elems) exclusive scan ----------------
__global__ __launch_bounds__(256) void scan1_kernel(
    const int* __restrict__ in, int* __restrict__ out, int* __restrict__ bsums, int n)
{
    __shared__ int s[256];
    int t = threadIdx.x;
    int base = blockIdx.x * 1024 + t * 4;
    int4 v = make_int4(0, 0, 0, 0);
    if (base < n) v = *(const int4*)(in + base);   // n % 4 == 0
    int tsum = v.x + v.y + v.z + v.w;
    s[t] = tsum;
    __syncthreads();
    for (int off = 1; off < 256; off <<= 1) {
        int add = (t >= off) ? s[t - off] : 0;
        __syncthreads();
        s[t] += add;
        __syncthreads();
    }
    if (t == 255) bsums[blockIdx.x] = s[255];
    int tprefix = (t > 0) ? s[t - 1] : 0;
    if (base < n) {
        int4 o;
        o.x = tprefix;
        o.y = tprefix + v.x;
        o.z = tprefix + v.x + v.y;
        o.w = tprefix + v.x + v.y + v.z;
        *(int4*)(out + base) = o;
    }
}

// ---------------- scan phase 2: scan of block sums (single block, nb <= 256) ----------------
__global__ __launch_bounds__(256) void scan2_kernel(int* __restrict__ bsums, int nb)
{
    __shared__ int s[256];
    int t = threadIdx.x;
    s[t] = (t < nb) ? bsums[t] : 0;
    __syncthreads();
    for (int off = 1; off < 256; off <<= 1) {
        int add = (t >= off) ? s[t - off] : 0;
        __syncthreads();
        s[t] += add;
        __syncthreads();
    }
    if (t < nb) bsums[t] = (t > 0) ? s[t - 1] : 0;
}

// ---------------- scan phase 3: add block offsets; write cursor copy; seal total ----------------
__global__ __launch_bounds__(256) void scan3_kernel(
    int* __restrict__ out, int* __restrict__ cur, const int* __restrict__ bsums,
    int n, int total)
{
    int t = threadIdx.x;
    int base = blockIdx.x * 1024 + t * 4;
    if (base < n) {
        int add = bsums[blockIdx.x];
        int4 v = *(const int4*)(out + base);
        v.x += add; v.y += add; v.z += add; v.w += add;
        *(int4*)(out + base) = v;
        *(int4*)(cur + base) = v;
    }
    if (blockIdx.x == 0 && t == 0) out[n] = total;
}

// ---------------- fill: scatter (neighbor, weight) into sorted order ----------------
__global__ __launch_bounds__(256) void fill_kernel(
    const int* __restrict__ ep, const int* __restrict__ ec, const float* __restrict__ ew,
    int* __restrict__ cur_p, int* __restrict__ cur_c,
    int2* __restrict__ sorted_p, int2* __restrict__ sorted_c)
{
    int e = blockIdx.x * 256 + threadIdx.x;
    if (e >= NE) return;
    int p = ep[e], c = ec[e];
    int wbits = __float_as_int(ew[e]);
    int pos = atomicAdd(&cur_p[p], 1);
    sorted_p[pos] = make_int2(c, wbits);
    int pos2 = atomicAdd(&cur_c[c], 1);
    sorted_c[pos2] = make_int2(p, wbits);
}

// ---------------- fused gather-aggregate + MLP (wave per row) ----------------
__global__ __launch_bounds__(256) void fused_kernel(
    const int2* __restrict__ sorted, const int* __restrict__ off,
    const float* __restrict__ selfemb, const float* __restrict__ nbremb,
    const float* __restrict__ w1, const float* __restrict__ b1,
    const float* __restrict__ g1, const float* __restrict__ be1,
    const float* __restrict__ w2, const float* __restrict__ b2,
    const float* __restrict__ g2, const float* __restrict__ be2,
    float* __restrict__ out)
{
    __shared__ float s_x[4][256];
    __shared__ float s_h[4][128];
    int wave = threadIdx.x >> 6;
    int lane = threadIdx.x & 63;
    int row = blockIdx.x * 4 + wave;   // grid sized exactly; rows % 4 == 0

    // ---- gather-aggregate this row's edge segment ----
    int start = off[row];
    int end   = off[row + 1];
    float acc0 = 0.f, acc1 = 0.f, deg = 0.f;
    for (int j = start; j < end; ++j) {
        int2 v = sorted[j];                 // broadcast (same addr all lanes)
        float w = __int_as_float(v.y);
        const float* nrow = nbremb + (size_t)v.x * DIM;
        deg  += w;                          // redundant per-lane, no reduce needed
        acc0 += w * nrow[lane];
        acc1 += w * nrow[lane + 64];
    }
    float inv = 1.0f / (deg + 1e-8f);

    const float* erow = selfemb + (size_t)row * DIM;
    s_x[wave][lane]       = erow[lane];
    s_x[wave][lane + 64]  = erow[lane + 64];
    s_x[wave][lane + 128] = acc0 * inv;
    s_x[wave][lane + 192] = acc1 * inv;
    __syncthreads();

    // ---- layer 1: h[lane], h[lane+64] ----
    float h0 = b1[lane];
    float h1 = b1[lane + 64];
    #pragma unroll 4
    for (int k = 0; k < 256; k += 4) {
        float4 xk = *(const float4*)&s_x[wave][k];
        const float* wk = w1 + (size_t)k * HID;
        h0 += xk.x * wk[lane];            h1 += xk.x * wk[lane + 64];
        h0 += xk.y * wk[HID + lane];      h1 += xk.y * wk[HID + lane + 64];
        h0 += xk.z * wk[2*HID + lane];    h1 += xk.z * wk[2*HID + lane + 64];
        h0 += xk.w * wk[3*HID + lane];    h1 += xk.w * wk[3*HID + lane + 64];
    }

    // LN over 128 (2 values/lane)
    float s = h0 + h1;
    float ss = h0 * h0 + h1 * h1;
    #pragma unroll
    for (int off2 = 32; off2; off2 >>= 1) {
        s  += __shfl_down(s, off2);
        ss += __shfl_down(ss, off2);
    }
    s  = __shfl(s, 0);
    ss = __shfl(ss, 0);
    float mu  = s * (1.0f / 128.0f);
    float var = ss * (1.0f / 128.0f) - mu * mu;
    float rstd = rsqrtf(var + 1e-5f);
    float n0 = (h0 - mu) * rstd * g1[lane]      + be1[lane];
    float n1 = (h1 - mu) * rstd * g1[lane + 64] + be1[lane + 64];
    n0 = fmaxf(n0, 0.0f);
    n1 = fmaxf(n1, 0.0f);
    s_h[wave][lane]      = n0;
    s_h[wave][lane + 64] = n1;
    __syncthreads();

    // ---- layer 2: out[lane] ----
    float acc = b2[lane];
    #pragma unroll 4
    for (int j = 0; j < 128; j += 4) {
        float4 hj = *(const float4*)&s_h[wave][j];
        const float* wj = w2 + (size_t)j * OUT;
        acc += hj.x * wj[lane];
        acc += hj.y * wj[OUT + lane];
        acc += hj.z * wj[2*OUT + lane];
        acc += hj.w * wj[3*OUT + lane];
    }

    // LN over 64
    float s2 = acc, ss2 = acc * acc;
    #pragma unroll
    for (int off2 = 32; off2; off2 >>= 1) {
        s2  += __shfl_down(s2, off2);
        ss2 += __shfl_down(ss2, off2);
    }
    s2  = __shfl(s2, 0);
    ss2 = __shfl(ss2, 0);
    float mu2  = s2 * (1.0f / 64.0f);
    float var2 = ss2 * (1.0f / 64.0f) - mu2 * mu2;
    float rstd2 = rsqrtf(var2 + 1e-5f);
    out[(size_t)row * OUT + lane] = (acc - mu2) * rstd2 * g2[lane] + be2[lane];
}

extern "C" void kernel_launch(void* const* d_in, const int* in_sizes, int n_in,
                              void* d_out, int out_size, void* d_ws, size_t ws_size,
                              hipStream_t stream) {
    const int*   ep   = (const int*)d_in[0];
    const int*   ec   = (const int*)d_in[1];
    const float* ew   = (const float*)d_in[2];
    const float* pemb = (const float*)d_in[3];
    const float* cemb = (const float*)d_in[4];
    const float* w1p  = (const float*)d_in[5];
    const float* b1p  = (const float*)d_in[6];
    const float* g1p  = (const float*)d_in[7];
    const float* be1p = (const float*)d_in[8];
    const float* w2p  = (const float*)d_in[9];
    const float* b2p  = (const float*)d_in[10];
    const float* g2p  = (const float*)d_in[11];
    const float* be2p = (const float*)d_in[12];
    const float* w1c  = (const float*)d_in[13];
    const float* b1c  = (const float*)d_in[14];
    const float* g1c  = (const float*)d_in[15];
    const float* be1c = (const float*)d_in[16];
    const float* w2c  = (const float*)d_in[17];
    const float* b2c  = (const float*)d_in[18];
    const float* g2c  = (const float*)d_in[19];
    const float* be2c = (const float*)d_in[20];

    // ---- workspace layout (ints, 64-element padded) ----
    int* wsi = (int*)d_ws;
    const int NP_PAD = 100032;   // NP, NP+1 <= 100032
    const int NC_PAD = 20032;    // NC, NC+1 <= 20032
    int* hist_p  = wsi;
    int* off_p   = hist_p + NP_PAD;
    int* cur_p   = off_p  + NP_PAD;
    int* hist_c  = cur_p  + NP_PAD;
    int* off_c   = hist_c + NC_PAD;
    int* cur_c   = off_c  + NC_PAD;
    int* bsums_p = cur_c  + NC_PAD;   // 128
    int* bsums_c = bsums_p + 128;     // 128
    int  meta_ints = 3 * NP_PAD + 3 * NC_PAD + 256;        // 360448, % 4 == 0
    int2* sorted_p = (int2*)(wsi + meta_ints);             // NE
    int2* sorted_c = sorted_p + NE;                        // NE

    // zero meta region (hist must be zeroed every call)
    zero4_kernel<<<1024, 256, 0, stream>>>((float4*)wsi, (size_t)meta_ints / 4);

    int eblocks = (NE + 255) / 256;
    hist_kernel<<<eblocks, 256, 0, stream>>>(ep, ec, hist_p, hist_c);

    // exclusive scans -> CSR offsets + cursors
    const int NB_P = (NP + 1023) / 1024;   // 98
    const int NB_C = (NC + 1023) / 1024;   // 20
    scan1_kernel<<<NB_P, 256, 0, stream>>>(hist_p, off_p, bsums_p, NP);
    scan2_kernel<<<1, 256, 0, stream>>>(bsums_p, NB_P);
    scan3_kernel<<<NB_P, 256, 0, stream>>>(off_p, cur_p, bsums_p, NP, NE);
    scan1_kernel<<<NB_C, 256, 0, stream>>>(hist_c, off_c, bsums_c, NC);
    scan2_kernel<<<1, 256, 0, stream>>>(bsums_c, NB_C);
    scan3_kernel<<<NB_C, 256, 0, stream>>>(off_c, cur_c, bsums_c, NC, NE);

    fill_kernel<<<eblocks, 256, 0, stream>>>(ep, ec, ew, cur_p, cur_c, sorted_p, sorted_c);

    float* out_p = (float*)d_out;            // [NP, 64]
    float* out_c = out_p + (size_t)NP * OUT; // [NC, 64]

    fused_kernel<<<NP / 4, 256, 0, stream>>>(sorted_p, off_p, pemb, cemb,
                                             w1p, b1p, g1p, be1p,
                                             w2p, b2p, g2p, be2p, out_p);
    fused_kernel<<<NC / 4, 256, 0, stream>>>(sorted_c, off_c, cemb, pemb,
                                             w1c, b1c, g1c, be1c,
                                             w2c, b2c, g2c, be2c, out_c);
}

// Round 3
// 1188.617 us; speedup vs baseline: 1.9996x; 1.1764x over previous
//
#include <hip/hip_runtime.h>
#include <cstddef>

#define NP 100000
#define NC 20000
#define NE 2000000
#define DIM 128
#define HID 128
#define OUTD 64

// ---------------- zero workspace region ----------------
__global__ void zero4_kernel(float4* p, size_t n4) {
    size_t i = blockIdx.x * (size_t)blockDim.x + threadIdx.x;
    size_t stride = (size_t)gridDim.x * blockDim.x;
    float4 z = make_float4(0.f, 0.f, 0.f, 0.f);
    for (; i < n4; i += stride) p[i] = z;
}

// ---------------- histogram ----------------
__global__ __launch_bounds__(256) void hist_kernel(
    const int* __restrict__ ep, const int* __restrict__ ec,
    int* __restrict__ hist_p, int* __restrict__ hist_c)
{
    int e = blockIdx.x * 256 + threadIdx.x;
    if (e >= NE) return;
    atomicAdd(&hist_p[ep[e]], 1);
    atomicAdd(&hist_c[ec[e]], 1);
}

// ---------------- scan phase 1 ----------------
__global__ __launch_bounds__(256) void scan1_kernel(
    const int* __restrict__ in, int* __restrict__ out, int* __restrict__ bsums, int n)
{
    __shared__ int s[256];
    int t = threadIdx.x;
    int base = blockIdx.x * 1024 + t * 4;
    int4 v = make_int4(0, 0, 0, 0);
    if (base < n) v = *(const int4*)(in + base);
    int tsum = v.x + v.y + v.z + v.w;
    s[t] = tsum;
    __syncthreads();
    for (int off = 1; off < 256; off <<= 1) {
        int add = (t >= off) ? s[t - off] : 0;
        __syncthreads();
        s[t] += add;
        __syncthreads();
    }
    if (t == 255) bsums[blockIdx.x] = s[255];
    int tprefix = (t > 0) ? s[t - 1] : 0;
    if (base < n) {
        int4 o;
        o.x = tprefix;
        o.y = tprefix + v.x;
        o.z = tprefix + v.x + v.y;
        o.w = tprefix + v.x + v.y + v.z;
        *(int4*)(out + base) = o;
    }
}

// ---------------- scan phase 2 ----------------
__global__ __launch_bounds__(256) void scan2_kernel(int* __restrict__ bsums, int nb)
{
    __shared__ int s[256];
    int t = threadIdx.x;
    s[t] = (t < nb) ? bsums[t] : 0;
    __syncthreads();
    for (int off = 1; off < 256; off <<= 1) {
        int add = (t >= off) ? s[t - off] : 0;
        __syncthreads();
        s[t] += add;
        __syncthreads();
    }
    if (t < nb) bsums[t] = (t > 0) ? s[t - 1] : 0;
}

// ---------------- scan phase 3 ----------------
__global__ __launch_bounds__(256) void scan3_kernel(
    int* __restrict__ out, int* __restrict__ cur, const int* __restrict__ bsums,
    int n, int total)
{
    int t = threadIdx.x;
    int base = blockIdx.x * 1024 + t * 4;
    if (base < n) {
        int add = bsums[blockIdx.x];
        int4 v = *(const int4*)(out + base);
        v.x += add; v.y += add; v.z += add; v.w += add;
        *(int4*)(out + base) = v;
        *(int4*)(cur + base) = v;
    }
    if (blockIdx.x == 0 && t == 0) out[n] = total;
}

// ---------------- fill sorted edge lists ----------------
__global__ __launch_bounds__(256) void fill_kernel(
    const int* __restrict__ ep, const int* __restrict__ ec, const float* __restrict__ ew,
    int* __restrict__ cur_p, int* __restrict__ cur_c,
    int2* __restrict__ sorted_p, int2* __restrict__ sorted_c)
{
    int e = blockIdx.x * 256 + threadIdx.x;
    if (e >= NE) return;
    int p = ep[e], c = ec[e];
    int wbits = __float_as_int(ew[e]);
    int pos = atomicAdd(&cur_p[p], 1);
    sorted_p[pos] = make_int2(c, wbits);
    int pos2 = atomicAdd(&cur_c[c], 1);
    sorted_c[pos2] = make_int2(p, wbits);
}

// ---------------- aggregate: wave per row, write msg/deg ----------------
__global__ __launch_bounds__(256) void agg_kernel(
    const int2* __restrict__ sorted, const int* __restrict__ off,
    const float* __restrict__ nbremb, float* __restrict__ msg)
{
    int wave = threadIdx.x >> 6;
    int lane = threadIdx.x & 63;
    int row = blockIdx.x * 4 + wave;   // grid sized exactly
    int start = off[row];
    int end   = off[row + 1];
    float acc0 = 0.f, acc1 = 0.f, deg = 0.f;
    for (int j = start; j < end; ++j) {
        int2 v = sorted[j];
        float w = __int_as_float(v.y);
        const float* nrow = nbremb + (size_t)v.x * DIM;
        deg  += w;
        acc0 += w * nrow[lane];
        acc1 += w * nrow[lane + 64];
    }
    float inv = 1.0f / (deg + 1e-8f);
    msg[(size_t)row * DIM + lane]      = acc0 * inv;
    msg[(size_t)row * DIM + lane + 64] = acc1 * inv;
}

// ---------------- MLP: 32 rows/block, LDS-blocked GEMM ----------------
// LDS: xs[32][256] (32KB, aliased by hs[32][132] after layer1) + ws[8192] (32KB)
__global__ __launch_bounds__(256, 2) void mlp_kernel(
    const float* __restrict__ selfemb, const float* __restrict__ msg,
    const float* __restrict__ w1, const float* __restrict__ b1,
    const float* __restrict__ g1, const float* __restrict__ be1,
    const float* __restrict__ w2, const float* __restrict__ b2,
    const float* __restrict__ g2, const float* __restrict__ be2,
    float* __restrict__ out)
{
    __shared__ float lds[16384];          // 64 KB
    float* xs = lds;                      // [32][256]
    float* ws = lds + 8192;               // w1 k-tile [64][128], later w2 [128][64]
    float* hs = lds;                      // [32][132] aliases xs (dead after layer1)

    int t = threadIdx.x;
    int rowbase = blockIdx.x * 32;

    // ---- stage xs = [emb | msg] for 32 rows ----
    #pragma unroll
    for (int i = 0; i < 8; ++i) {
        int li = i * 1024 + t * 4;
        int row = li >> 8;
        int col = li & 255;
        float4 v;
        if (col < 128) v = *(const float4*)&selfemb[(size_t)(rowbase + row) * DIM + col];
        else           v = *(const float4*)&msg[(size_t)(rowbase + row) * DIM + (col - 128)];
        *(float4*)&xs[li] = v;
    }
    __syncthreads();

    // ---- layer 1: acc[4 rows][4 cols] per thread ----
    int ct = t & 31;        // col-tile -> cols 4*ct..+3
    int rt = t >> 5;        // row-tile -> rows 4*rt..+3
    int c0 = ct * 4;
    int r0 = rt * 4;

    float acc[4][4];
    {
        float4 bb = *(const float4*)&b1[c0];
        #pragma unroll
        for (int r = 0; r < 4; ++r) {
            acc[r][0] = bb.x; acc[r][1] = bb.y; acc[r][2] = bb.z; acc[r][3] = bb.w;
        }
    }

    for (int kt = 0; kt < 4; ++kt) {
        // stage w1 tile [64][128]
        #pragma unroll
        for (int i = 0; i < 8; ++i) {
            int li = i * 1024 + t * 4;
            *(float4*)&ws[li] = *(const float4*)&w1[kt * 8192 + li];
        }
        __syncthreads();

        #pragma unroll 4
        for (int k = 0; k < 64; k += 4) {
            float4 wa = *(float4*)&ws[(k    ) * 128 + c0];
            float4 wb = *(float4*)&ws[(k + 1) * 128 + c0];
            float4 wc = *(float4*)&ws[(k + 2) * 128 + c0];
            float4 wd = *(float4*)&ws[(k + 3) * 128 + c0];
            #pragma unroll
            for (int r = 0; r < 4; ++r) {
                float4 x4 = *(float4*)&xs[(r0 + r) * 256 + kt * 64 + k];
                acc[r][0] += x4.x * wa.x + x4.y * wb.x + x4.z * wc.x + x4.w * wd.x;
                acc[r][1] += x4.x * wa.y + x4.y * wb.y + x4.z * wc.y + x4.w * wd.y;
                acc[r][2] += x4.x * wa.z + x4.y * wb.z + x4.z * wc.z + x4.w * wd.z;
                acc[r][3] += x4.x * wa.w + x4.y * wb.w + x4.z * wc.w + x4.w * wd.w;
            }
        }
        __syncthreads();   // readers done before next stage / hs alias
    }

    // ---- LN1 + ReLU -> hs (aliases xs; safe after the barrier above) ----
    {
        float4 gg = *(const float4*)&g1[c0];
        float4 bb = *(const float4*)&be1[c0];
        #pragma unroll
        for (int r = 0; r < 4; ++r) {
            float s = acc[r][0] + acc[r][1] + acc[r][2] + acc[r][3];
            float q = acc[r][0]*acc[r][0] + acc[r][1]*acc[r][1]
                    + acc[r][2]*acc[r][2] + acc[r][3]*acc[r][3];
            #pragma unroll
            for (int m = 16; m; m >>= 1) {
                s += __shfl_xor(s, m);
                q += __shfl_xor(q, m);
            }
            float mu  = s * (1.0f / 128.0f);
            float var = q * (1.0f / 128.0f) - mu * mu;
            float rstd = rsqrtf(var + 1e-5f);
            float4 h;
            h.x = fmaxf((acc[r][0] - mu) * rstd * gg.x + bb.x, 0.f);
            h.y = fmaxf((acc[r][1] - mu) * rstd * gg.y + bb.y, 0.f);
            h.z = fmaxf((acc[r][2] - mu) * rstd * gg.z + bb.z, 0.f);
            h.w = fmaxf((acc[r][3] - mu) * rstd * gg.w + bb.w, 0.f);
            *(float4*)&hs[(r0 + r) * 132 + c0] = h;
        }
    }
    __syncthreads();

    // ---- stage w2 [128][64] into ws ----
    #pragma unroll
    for (int i = 0; i < 8; ++i) {
        int li = i * 1024 + t * 4;
        *(float4*)&ws[li] = *(const float4*)&w2[li];
    }
    __syncthreads();

    // ---- layer 2: acc2[2 rows][4 cols] per thread ----
    int ct2 = t & 15;       // cols 4*ct2..+3
    int rt2 = t >> 4;       // rows 2*rt2..+1
    int c2 = ct2 * 4;
    int r2 = rt2 * 2;

    float acc2[2][4];
    {
        float4 bb = *(const float4*)&b2[c2];
        #pragma unroll
        for (int r = 0; r < 2; ++r) {
            acc2[r][0] = bb.x; acc2[r][1] = bb.y; acc2[r][2] = bb.z; acc2[r][3] = bb.w;
        }
    }

    #pragma unroll 4
    for (int k = 0; k < 128; k += 4) {
        float4 wa = *(float4*)&ws[(k    ) * 64 + c2];
        float4 wb = *(float4*)&ws[(k + 1) * 64 + c2];
        float4 wc = *(float4*)&ws[(k + 2) * 64 + c2];
        float4 wd = *(float4*)&ws[(k + 3) * 64 + c2];
        #pragma unroll
        for (int r = 0; r < 2; ++r) {
            float4 x4 = *(float4*)&hs[(r2 + r) * 132 + k];
            acc2[r][0] += x4.x * wa.x + x4.y * wb.x + x4.z * wc.x + x4.w * wd.x;
            acc2[r][1] += x4.x * wa.y + x4.y * wb.y + x4.z * wc.y + x4.w * wd.y;
            acc2[r][2] += x4.x * wa.z + x4.y * wb.z + x4.z * wc.z + x4.w * wd.z;
            acc2[r][3] += x4.x * wa.w + x4.y * wb.w + x4.z * wc.w + x4.w * wd.w;
        }
    }

    // ---- LN2 -> out ----
    {
        float4 gg = *(const float4*)&g2[c2];
        float4 bb = *(const float4*)&be2[c2];
        #pragma unroll
        for (int r = 0; r < 2; ++r) {
            float s = acc2[r][0] + acc2[r][1] + acc2[r][2] + acc2[r][3];
            float q = acc2[r][0]*acc2[r][0] + acc2[r][1]*acc2[r][1]
                    + acc2[r][2]*acc2[r][2] + acc2[r][3]*acc2[r][3];
            #pragma unroll
            for (int m = 8; m; m >>= 1) {
                s += __shfl_xor(s, m);
                q += __shfl_xor(q, m);
            }
            float mu  = s * (1.0f / 64.0f);
            float var = q * (1.0f / 64.0f) - mu * mu;
            float rstd = rsqrtf(var + 1e-5f);
            float4 o;
            o.x = (acc2[r][0] - mu) * rstd * gg.x + bb.x;
            o.y = (acc2[r][1] - mu) * rstd * gg.y + bb.y;
            o.z = (acc2[r][2] - mu) * rstd * gg.z + bb.z;
            o.w = (acc2[r][3] - mu) * rstd * gg.w + bb.w;
            *(float4*)&out[(size_t)(rowbase + r2 + r) * OUTD + c2] = o;
        }
    }
}

extern "C" void kernel_launch(void* const* d_in, const int* in_sizes, int n_in,
                              void* d_out, int out_size, void* d_ws, size_t ws_size,
                              hipStream_t stream) {
    const int*   ep   = (const int*)d_in[0];
    const int*   ec   = (const int*)d_in[1];
    const float* ew   = (const float*)d_in[2];
    const float* pemb = (const float*)d_in[3];
    const float* cemb = (const float*)d_in[4];
    const float* w1p  = (const float*)d_in[5];
    const float* b1p  = (const float*)d_in[6];
    const float* g1p  = (const float*)d_in[7];
    const float* be1p = (const float*)d_in[8];
    const float* w2p  = (const float*)d_in[9];
    const float* b2p  = (const float*)d_in[10];
    const float* g2p  = (const float*)d_in[11];
    const float* be2p = (const float*)d_in[12];
    const float* w1c  = (const float*)d_in[13];
    const float* b1c  = (const float*)d_in[14];
    const float* g1c  = (const float*)d_in[15];
    const float* be1c = (const float*)d_in[16];
    const float* w2c  = (const float*)d_in[17];
    const float* b2c  = (const float*)d_in[18];
    const float* g2c  = (const float*)d_in[19];
    const float* be2c = (const float*)d_in[20];

    // ---- workspace layout ----
    int* wsi = (int*)d_ws;
    const int NP_PAD = 100032;
    const int NC_PAD = 20032;
    int* hist_p  = wsi;
    int* off_p   = hist_p + NP_PAD;
    int* cur_p   = off_p  + NP_PAD;
    int* hist_c  = cur_p  + NP_PAD;
    int* off_c   = hist_c + NC_PAD;
    int* cur_c   = off_c  + NC_PAD;
    int* bsums_p = cur_c  + NC_PAD;   // 128
    int* bsums_c = bsums_p + 128;     // 128
    int  meta_ints = 3 * NP_PAD + 3 * NC_PAD + 256;
    int2* sorted_p = (int2*)(wsi + meta_ints);             // NE
    int2* sorted_c = sorted_p + NE;                        // NE
    float* pmsg = (float*)(sorted_c + NE);                 // NP*DIM
    float* cmsg = pmsg + (size_t)NP * DIM;                 // NC*DIM

    // zero meta region (hist must be zeroed every call)
    zero4_kernel<<<1024, 256, 0, stream>>>((float4*)wsi, (size_t)meta_ints / 4);

    int eblocks = (NE + 255) / 256;
    hist_kernel<<<eblocks, 256, 0, stream>>>(ep, ec, hist_p, hist_c);

    const int NB_P = (NP + 1023) / 1024;   // 98
    const int NB_C = (NC + 1023) / 1024;   // 20
    scan1_kernel<<<NB_P, 256, 0, stream>>>(hist_p, off_p, bsums_p, NP);
    scan2_kernel<<<1, 256, 0, stream>>>(bsums_p, NB_P);
    scan3_kernel<<<NB_P, 256, 0, stream>>>(off_p, cur_p, bsums_p, NP, NE);
    scan1_kernel<<<NB_C, 256, 0, stream>>>(hist_c, off_c, bsums_c, NC);
    scan2_kernel<<<1, 256, 0, stream>>>(bsums_c, NB_C);
    scan3_kernel<<<NB_C, 256, 0, stream>>>(off_c, cur_c, bsums_c, NC, NE);

    fill_kernel<<<eblocks, 256, 0, stream>>>(ep, ec, ew, cur_p, cur_c, sorted_p, sorted_c);

    agg_kernel<<<NP / 4, 256, 0, stream>>>(sorted_p, off_p, cemb, pmsg);
    agg_kernel<<<NC / 4, 256, 0, stream>>>(sorted_c, off_c, pemb, cmsg);

    float* out_p = (float*)d_out;            // [NP, 64]
    float* out_c = out_p + (size_t)NP * OUTD;

    mlp_kernel<<<NP / 32, 256, 0, stream>>>(pemb, pmsg,
                                            w1p, b1p, g1p, be1p,
                                            w2p, b2p, g2p, be2p, out_p);
    mlp_kernel<<<NC / 32, 256, 0, stream>>>(cemb, cmsg,
                                            w1c, b1c, g1c, be1c,
                                            w2c, b2c, g2c, be2c, out_c);
}